// Round 6
// baseline (2082.360 us; speedup 1.0000x reference)
//
#include <hip/hip_runtime.h>
#include <hip/hip_bf16.h>

#define N_NODES 100000
#define N_EDGES 3200000
#define N_GRAPHS 256
#define D_IN 320
#define D_H 64

#define NBIN 391                    // ceil(N_NODES / 256) bins of 256 dst nodes
#define BIN_CAP 12288               // mean bin load 8186, sigma~90 -> +45 sigma
#define HIST_BLOCKS 256
#define HIST_CHUNK ((N_EDGES + HIST_BLOCKS - 1) / HIST_BLOCKS)
#define PART_BLOCKS 200
#define PART_CHUNK ((N_EDGES + PART_BLOCKS - 1) / PART_BLOCKS)   // 16000

#define NKB 13                      // src buckets of 8192 nodes (2 MB of u, fits XCD L2)
#define NPB 391                     // nodes per fused-agg block (256 blocks cover 100096)

// ---------------- CSR build (block-private chunk partition) ----------------

__global__ __launch_bounds__(256) void k_hist(const int* __restrict__ dst,
                                              int* __restrict__ ghist) {
    __shared__ int lh[NBIN];
    for (int i = threadIdx.x; i < NBIN; i += 256) lh[i] = 0;
    __syncthreads();
    int beg = blockIdx.x * HIST_CHUNK;
    int end = min(beg + HIST_CHUNK, N_EDGES);
    for (int e = beg + threadIdx.x; e < end; e += 256)
        atomicAdd(&lh[dst[e] >> 8], 1);
    __syncthreads();
    for (int i = threadIdx.x; i < NBIN; i += 256)
        if (lh[i]) atomicAdd(&ghist[i], lh[i]);
}

__global__ __launch_bounds__(512) void k_scanbins(const int* __restrict__ ghist,
                                                  int* __restrict__ binbase,
                                                  int* __restrict__ gcur,
                                                  int* __restrict__ rp2) {
    __shared__ int sa[512], sb[512];
    int t = threadIdx.x;
    int v = (t < NBIN) ? ghist[t] : 0;
    sa[t] = v;
    __syncthreads();
    int* in = sa; int* out = sb;
    for (int off = 1; off < 512; off <<= 1) {
        out[t] = in[t] + (t >= off ? in[t - off] : 0);
        __syncthreads();
        int* tmp = in; in = out; out = tmp;
    }
    int excl = in[t] - v;
    if (t < NBIN) { binbase[t] = excl; gcur[t] = excl; }
    if (t == 511) { binbase[NBIN] = in[511]; rp2[(size_t)N_NODES * NKB] = in[511]; }
}

// partition edges into 391 bins; each block reserves a private contiguous
// chunk per bin (one global atomic per (block,bin)).
__global__ __launch_bounds__(256) void k_part(const int* __restrict__ src,
                                              const int* __restrict__ dst,
                                              int* __restrict__ gcur,
                                              int* __restrict__ ebuf) {
    __shared__ int lh[NBIN], gb[NBIN], cur[NBIN];
    for (int i = threadIdx.x; i < NBIN; i += 256) { lh[i] = 0; cur[i] = 0; }
    __syncthreads();
    int beg = blockIdx.x * PART_CHUNK;
    int end = min(beg + PART_CHUNK, N_EDGES);
    for (int e = beg + threadIdx.x; e < end; e += 256)
        atomicAdd(&lh[dst[e] >> 8], 1);
    __syncthreads();
    for (int i = threadIdx.x; i < NBIN; i += 256)
        gb[i] = lh[i] ? atomicAdd(&gcur[i], lh[i]) : 0;
    __syncthreads();
    for (int e = beg + threadIdx.x; e < end; e += 256) {
        int d = dst[e], s = src[e];
        int bin = d >> 8;
        int r = atomicAdd(&cur[bin], 1);
        ebuf[gb[bin] + r] = ((d & 255) << 17) | s;   // dst-low-8 | src(17b)
    }
}

// one block per bin: counting-sort by (dst_local, src_bucket); writes col
// coalesced, emits rp2[(node)*NKB + k] run boundaries and dinv.
__global__ __launch_bounds__(256) void k_sortbin(const int* __restrict__ binbase,
                                                 const int* __restrict__ ebuf,
                                                 int* __restrict__ col,
                                                 int* __restrict__ rp2,
                                                 float* __restrict__ dinv) {
    __shared__ int hc[4096], sc[4096];
    __shared__ int sa[256], sb[256];
    __shared__ int scol[BIN_CAP];
    int b = blockIdx.x, t = threadIdx.x;
    int d0 = b << 8;
    int e0 = binbase[b], e1 = binbase[b + 1];
    for (int i = t; i < 4096; i += 256) hc[i] = 0;
    __syncthreads();
    for (int i = e0 + t; i < e1; i += 256) {
        int pk = ebuf[i];
        int dl = pk >> 17, s = pk & 0x1FFFF;
        atomicAdd(&hc[(dl << 4) | (s >> 13)], 1);
    }
    __syncthreads();
    // thread t owns keys [t*16, t*16+16) == node (d0+t)'s buckets (13 used)
    int loc[16]; int sum = 0;
#pragma unroll
    for (int q = 0; q < 16; ++q) { loc[q] = sum; sum += hc[t * 16 + q]; }
    sa[t] = sum;
    __syncthreads();
    int* in = sa; int* out = sb;
    for (int o = 1; o < 256; o <<= 1) {
        out[t] = in[t] + (t >= o ? in[t - o] : 0);
        __syncthreads();
        int* tm = in; in = out; out = tm;
    }
    int tbase = in[t] - sum;           // exclusive prefix of thread sums
#pragma unroll
    for (int q = 0; q < 16; ++q) sc[t * 16 + q] = tbase + loc[q];
    int node = d0 + t;
    if (node < N_NODES) {
        dinv[node] = rsqrtf((float)(sum + 1));   // +1 self loop
#pragma unroll
        for (int q = 0; q < NKB; ++q)
            rp2[(size_t)node * NKB + q] = e0 + tbase + loc[q];
    }
    __syncthreads();
    for (int i = e0 + t; i < e1; i += 256) {
        int pk = ebuf[i];
        int dl = pk >> 17, s = pk & 0x1FFFF;
        int p = atomicAdd(&sc[(dl << 4) | (s >> 13)], 1);
        if (p < BIN_CAP) scol[p] = s;
    }
    __syncthreads();
    int n = e1 - e0;
    for (int i = t; i < n; i += 256) col[e0 + i] = scol[i];
}

// ---------------- tiled GEMM transform (layer 1: 320 -> 64) ----------------
template<int K>
__global__ __launch_bounds__(256) void k_gemm(const float* __restrict__ A,
                                              const float* __restrict__ W,
                                              const float* __restrict__ dinv,
                                              float* __restrict__ u) {
    __shared__ __align__(16) float xt[64][68];
    __shared__ __align__(16) float ws[64][68];
    int t = threadIdx.x;
    int ti = t & 15;
    int tj = t >> 4;
    int node0 = blockIdx.x * 64;
    float acc[4][4] = {{0.f}};

    for (int kc = 0; kc < K; kc += 64) {
        if (kc) __syncthreads();
#pragma unroll
        for (int p = 0; p < 4; ++p) {
            int m = tj + 16 * p;
            int node = node0 + m;
            if (node >= N_NODES) node = N_NODES - 1;
            float4 v = *(const float4*)(A + (size_t)node * K + kc + 4 * ti);
            xt[4 * ti + 0][m] = v.x;
            xt[4 * ti + 1][m] = v.y;
            xt[4 * ti + 2][m] = v.z;
            xt[4 * ti + 3][m] = v.w;
            float4 wv = *(const float4*)(W + (size_t)(kc + m) * D_H + 4 * ti);
            *(float4*)&ws[m][4 * ti] = wv;
        }
        __syncthreads();
#pragma unroll 16
        for (int k = 0; k < 64; ++k) {
            float4 xv = *(const float4*)&xt[k][4 * tj];
            float4 wv = *(const float4*)&ws[k][4 * ti];
            float xa[4] = {xv.x, xv.y, xv.z, xv.w};
            float wa[4] = {wv.x, wv.y, wv.z, wv.w};
#pragma unroll
            for (int i = 0; i < 4; ++i)
#pragma unroll
                for (int j = 0; j < 4; ++j)
                    acc[i][j] = fmaf(xa[i], wa[j], acc[i][j]);
        }
    }
#pragma unroll
    for (int i = 0; i < 4; ++i) {
        int node = node0 + 4 * tj + i;
        if (node < N_NODES) {
            float dv = dinv[node];
            float4 o = make_float4(acc[i][0] * dv, acc[i][1] * dv,
                                   acc[i][2] * dv, acc[i][3] * dv);
            *(float4*)(u + (size_t)node * D_H + 4 * ti) = o;
        }
    }
}

// ---------------- fused bucketed aggregation ----------------
// Per block: 391 dst nodes, LDS accumulator, 13 src-bucket phases with
// __syncthreads so all co-resident blocks stream the same 2 MB u-bucket.

__device__ __forceinline__ void bucket_gather(const float* __restrict__ uin,
                                              const int* __restrict__ rp2,
                                              const int* __restrict__ col,
                                              float (*hacc)[64],
                                              int base, int w, int lane, int nslots) {
    for (int k = 0; k < NKB; ++k) {
        int s = 0;
        for (; s + 1 < nslots; s += 2) {          // 2-node interleave for MLP
            int lA = w + 8 * s, lB = lA + 8;
            int nA = base + lA, nB = base + lB;
            int eA = rp2[(size_t)nA * NKB + k], endA = rp2[(size_t)nA * NKB + k + 1];
            int eB = rp2[(size_t)nB * NKB + k], endB = rp2[(size_t)nB * NKB + k + 1];
            float aA = 0.f, aB = 0.f;
            while (eA < endA && eB < endB) {
                float vA = uin[(size_t)col[eA] * D_H + lane];
                float vB = uin[(size_t)col[eB] * D_H + lane];
                aA += vA; aB += vB; ++eA; ++eB;
            }
            for (; eA < endA; ++eA) aA += uin[(size_t)col[eA] * D_H + lane];
            for (; eB < endB; ++eB) aB += uin[(size_t)col[eB] * D_H + lane];
            hacc[lA][lane] += aA;
            hacc[lB][lane] += aB;
        }
        if (s < nslots) {
            int lA = w + 8 * s;
            int nA = base + lA;
            int eA = rp2[(size_t)nA * NKB + k], endA = rp2[(size_t)nA * NKB + k + 1];
            float aA = 0.f;
            for (; eA < endA; ++eA) aA += uin[(size_t)col[eA] * D_H + lane];
            hacc[lA][lane] += aA;
        }
        __syncthreads();
    }
}

__device__ __forceinline__ int wave_slots(int base, int w) {
    int maxn = min(NPB, N_NODES - base);
    return (maxn > w) ? ((maxn - w + 7) >> 3) : 0;
}

// agg(uin, b) -> relu -> xform(W) -> uout  (layers 1->2 and 2->3)
__global__ __launch_bounds__(512) void k_fused(const float* __restrict__ uin,
                                               const int* __restrict__ rp2,
                                               const int* __restrict__ col,
                                               const float* __restrict__ dinv,
                                               const float* __restrict__ b,
                                               const float* __restrict__ W,
                                               float* __restrict__ uout) {
    __shared__ float hacc[NPB][64];
    __shared__ float Ws[64][64];
    int t = threadIdx.x, w = t >> 6, lane = t & 63;
    int base = blockIdx.x * NPB;
    for (int i = t; i < NPB * 16; i += 512) ((float4*)hacc)[i] = make_float4(0, 0, 0, 0);
    for (int i = t; i < 1024; i += 512) ((float4*)Ws)[i] = ((const float4*)W)[i];
    __syncthreads();
    int nslots = wave_slots(base, w);
    bucket_gather(uin, rp2, col, hacc, base, w, lane, nslots);
    for (int s = 0; s < nslots; ++s) {
        int nl = w + 8 * s, n = base + nl;
        float dv = dinv[n];
        float hv = (hacc[nl][lane] + uin[(size_t)n * D_H + lane]) * dv + b[lane];
        hv = fmaxf(hv, 0.f);
        float acc = 0.f;
#pragma unroll
        for (int kk = 0; kk < 64; ++kk)
            acc = fmaf(__shfl(hv, kk, 64), Ws[kk][lane], acc);
        uout[(size_t)n * D_H + lane] = acc * dv;
    }
}

// agg(uin, b3) -> dot(Wl) -> val   (layer 3 + head)
__global__ __launch_bounds__(512) void k_fused_dot(const float* __restrict__ uin,
                                                   const int* __restrict__ rp2,
                                                   const int* __restrict__ col,
                                                   const float* __restrict__ dinv,
                                                   const float* __restrict__ b,
                                                   const float* __restrict__ Wl,
                                                   float* __restrict__ val) {
    __shared__ float hacc[NPB][64];
    int t = threadIdx.x, w = t >> 6, lane = t & 63;
    int base = blockIdx.x * NPB;
    for (int i = t; i < NPB * 16; i += 512) ((float4*)hacc)[i] = make_float4(0, 0, 0, 0);
    __syncthreads();
    int nslots = wave_slots(base, w);
    bucket_gather(uin, rp2, col, hacc, base, w, lane, nslots);
    float wl = Wl[lane];
    for (int s = 0; s < nslots; ++s) {
        int nl = w + 8 * s, n = base + nl;
        float hv = (hacc[nl][lane] + uin[(size_t)n * D_H + lane]) * dinv[n] + b[lane];
        float v = hv * wl;
#pragma unroll
        for (int m = 32; m > 0; m >>= 1) v += __shfl_xor(v, m, 64);
        if (lane == 0) val[n] = v;
    }
}

// one block per graph: batch is sorted, binary-search the segment, reduce.
__global__ __launch_bounds__(256) void k_gpool(const float* __restrict__ val,
                                               const int* __restrict__ batch,
                                               const float* __restrict__ bl,
                                               float* __restrict__ out) {
    int g = blockIdx.x;
    int l = 0, r = N_NODES;
    while (l < r) { int m = (l + r) >> 1; if (batch[m] < g) l = m + 1; else r = m; }
    int lo = l;
    r = N_NODES;
    while (l < r) { int m = (l + r) >> 1; if (batch[m] < g + 1) l = m + 1; else r = m; }
    int hi = l;
    float s = 0.0f;
    for (int i = lo + threadIdx.x; i < hi; i += 256) s += val[i];
#pragma unroll
    for (int m = 32; m > 0; m >>= 1) s += __shfl_xor(s, m, 64);
    __shared__ float red[4];
    int wid = threadIdx.x >> 6, lane = threadIdx.x & 63;
    if (lane == 0) red[wid] = s;
    __syncthreads();
    if (threadIdx.x == 0) {
        float t = red[0] + red[1] + red[2] + red[3];
        out[g] = t / fmaxf((float)(hi - lo), 1.0f) + bl[0];
    }
}

// ---------------- launch ----------------

extern "C" void kernel_launch(void* const* d_in, const int* in_sizes, int n_in,
                              void* d_out, int out_size, void* d_ws, size_t ws_size,
                              hipStream_t stream) {
    const float* x   = (const float*)d_in[0];
    const int*   ei  = (const int*)d_in[1];
    const int*   bat = (const int*)d_in[2];
    const float* W1  = (const float*)d_in[3];
    const float* b1  = (const float*)d_in[4];
    const float* W2  = (const float*)d_in[5];
    const float* b2  = (const float*)d_in[6];
    const float* W3  = (const float*)d_in[7];
    const float* b3  = (const float*)d_in[8];
    const float* Wl  = (const float*)d_in[9];
    const float* bl  = (const float*)d_in[10];
    float* out = (float*)d_out;

    char* p = (char*)d_ws;
    auto alloc = [&](size_t bytes) -> void* {
        void* r = (void*)p;
        p += (bytes + 255) & ~(size_t)255;
        return r;
    };
    int*   ghist   = (int*)alloc((size_t)NBIN * 4);
    int*   binbase = (int*)alloc((size_t)(NBIN + 1) * 4);
    int*   gcur    = (int*)alloc((size_t)NBIN * 4);
    int*   rp2     = (int*)alloc(((size_t)N_NODES * NKB + 1) * 4);
    float* dinv    = (float*)alloc((size_t)N_NODES * 4);
    int*   colb    = (int*)alloc((size_t)N_EDGES * 4);
    int*   ebuf    = (int*)alloc((size_t)N_EDGES * 4);
    float* u1      = (float*)alloc((size_t)N_NODES * D_H * 4);
    float* u2      = (float*)alloc((size_t)N_NODES * D_H * 4);
    float* val     = (float*)alloc((size_t)N_NODES * 4);

    hipMemsetAsync(ghist, 0, (size_t)NBIN * 4, stream);

    const int* srcp = ei;
    const int* dstp = ei + N_EDGES;

    int gbl = (N_NODES + 63) / 64;

    // CSR build (src-bucketed, rp2 run boundaries)
    k_hist<<<HIST_BLOCKS, 256, 0, stream>>>(dstp, ghist);
    k_scanbins<<<1, 512, 0, stream>>>(ghist, binbase, gcur, rp2);
    k_part<<<PART_BLOCKS, 256, 0, stream>>>(srcp, dstp, gcur, ebuf);
    k_sortbin<<<NBIN, 256, 0, stream>>>(binbase, ebuf, colb, rp2, dinv);

    // layer 1 transform: 320 -> 64
    k_gemm<D_IN><<<gbl, 256, 0, stream>>>(x, W1, dinv, u1);
    // agg1 + relu + xform(W2)
    k_fused<<<256, 512, 0, stream>>>(u1, rp2, colb, dinv, b1, W2, u2);
    // agg2 + relu + xform(W3)
    k_fused<<<256, 512, 0, stream>>>(u2, rp2, colb, dinv, b2, W3, u1);
    // agg3 + head dot
    k_fused_dot<<<256, 512, 0, stream>>>(u1, rp2, colb, dinv, b3, Wl, val);

    // pooling
    k_gpool<<<N_GRAPHS, 256, 0, stream>>>(val, bat, bl, out);
}